// Round 1
// baseline (1054.233 us; speedup 1.0000x reference)
//
#include <hip/hip_runtime.h>

#define HW   36864      // 192*192
#define NPOS 73728      // B*HW, B=2
#define NBLK 288        // NPOS/256
#define EPSV 1e-5f

// channel-slot layout in workspace (each slot = NPOS floats)
#define S1_HF1  0
#define S1_FD1  20
#define S1_PHU1 50
#define S1_PHL1 70
#define S1_HD1  90
#define S2_HF2  160
#define S2_FD2  170
#define S2_PHU2 200
#define S2_PHL2 210
#define S2_HD2  220
#define S3_FU   0       // reuse stage-1 slots (dead by stage 3)
#define S3_HU   20
#define S3_PU   50
#define ST3_FU  290     // stat-channel bases for stage 3
#define ST3_HU  310
#define ST3_PU  340
#define NSLOT 290
#define NSTAT 410

// ---------------------------------------------------------------------------
// Generic per-position conv + stats accumulation.
// Each thread owns one position; acc[COUT] lives in VGPRs; weight reads are
// wave-uniform -> scalar loads; stats via shfl butterfly + LDS + atomicAdd.
// ---------------------------------------------------------------------------
template<int CIN, int COUT, class F>
__device__ __forceinline__ void conv_cbr(F fetch, const float* __restrict__ w,
                                         float* __restrict__ y, int pos,
                                         float* __restrict__ sumA,
                                         float* __restrict__ sumqA,
                                         int stat0, float* red)
{
    float acc[COUT];
#pragma unroll
    for (int o = 0; o < COUT; ++o) acc[o] = 0.f;

#pragma unroll 2
    for (int c = 0; c < CIN; ++c) {
        float x = fetch(c);
#pragma unroll
        for (int o = 0; o < COUT; ++o)
            acc[o] = fmaf(w[o * CIN + c], x, acc[o]);
    }

#pragma unroll
    for (int o = 0; o < COUT; ++o)
        y[o * NPOS + pos] = acc[o];

    int lane = threadIdx.x & 63;
    int wv   = threadIdx.x >> 6;
#pragma unroll
    for (int o = 0; o < COUT; ++o) {
        float s = acc[o];
        float q = acc[o] * acc[o];
#pragma unroll
        for (int i = 1; i < 64; i <<= 1) {
            s += __shfl_xor(s, i, 64);
            q += __shfl_xor(q, i, 64);
        }
        if (lane == 0) {
            red[(wv * COUT + o) * 2]     = s;
            red[(wv * COUT + o) * 2 + 1] = q;
        }
    }
    __syncthreads();
    if (threadIdx.x < COUT) {
        int o = threadIdx.x;
        float s = 0.f, q = 0.f;
#pragma unroll
        for (int k = 0; k < 4; ++k) {
            s += red[(k * COUT + o) * 2];
            q += red[(k * COUT + o) * 2 + 1];
        }
        atomicAdd(&sumA[stat0 + o], s);
        atomicAdd(&sumqA[stat0 + o], q);
    }
}

// ---------------------------------------------------------------------------
// Stage 1: hf1, fd1, phu1, phl1, hd1  (raw inputs -> raw y + stats)
// ---------------------------------------------------------------------------
__global__ void __launch_bounds__(256) stage1_kernel(
    const float* __restrict__ xp, const float* __restrict__ xh,
    const float* __restrict__ xf, const float* __restrict__ p_fea,
    const float* __restrict__ h_fea,
    const float* __restrict__ w_hf1, const float* __restrict__ w_fd1,
    const float* __restrict__ w_phu1, const float* __restrict__ w_phl1,
    const float* __restrict__ w_hd1, float* __restrict__ ws)
{
    __shared__ float red[4 * 70 * 2];
    int pos = blockIdx.x * 256 + threadIdx.x;
    int b = (pos >= HW) ? 1 : 0;
    int s = pos - b * HW;
    float* y     = ws;
    float* sumA  = ws + (size_t)NSLOT * NPOS;
    float* sumqA = sumA + NSTAT;

    switch (blockIdx.y) {
    case 0: { // hf1: [xh1; xh2] (20) -> 20
        const float* xb = xh + ((size_t)b * 30 + 10) * HW + s;
        conv_cbr<20, 20>([&](int c) { return xb[c * HW]; },
                         w_hf1, y + (size_t)S1_HF1 * NPOS, pos, sumA, sumqA, S1_HF1, red);
        break; }
    case 1: { // fd1: [h_fea; xf1] (266) -> 30
        const float* hb  = h_fea + (size_t)b * 256 * HW + s;
        const float* xf1 = xf + ((size_t)b * 20 + 10) * HW + s;
        conv_cbr<266, 30>([&](int c) { return (c < 256) ? hb[c * HW] : xf1[(c - 256) * HW]; },
                          w_fd1, y + (size_t)S1_FD1 * NPOS, pos, sumA, sumqA, S1_FD1, red);
        break; }
    case 2: { // phu1: xp[1:5] (40) -> 20
        const float* xb = xp + ((size_t)b * 70 + 10) * HW + s;
        conv_cbr<40, 20>([&](int c) { return xb[c * HW]; },
                         w_phu1, y + (size_t)S1_PHU1 * NPOS, pos, sumA, sumqA, S1_PHU1, red);
        break; }
    case 3: { // phl1: xp[5:7] (20) -> 20
        const float* xb = xp + ((size_t)b * 70 + 50) * HW + s;
        conv_cbr<20, 20>([&](int c) { return xb[c * HW]; },
                         w_phl1, y + (size_t)S1_PHL1 * NPOS, pos, sumA, sumqA, S1_PHL1, red);
        break; }
    default: { // hd1: [p_fea; xh1; xh2] (276) -> 70
        const float* pb = p_fea + (size_t)b * 256 * HW + s;
        const float* xb = xh + ((size_t)b * 30 + 10) * HW + s;
        conv_cbr<276, 70>([&](int c) { return (c < 256) ? pb[c * HW] : xb[(c - 256) * HW]; },
                          w_hd1, y + (size_t)S1_HD1 * NPOS, pos, sumA, sumqA, S1_HD1, red);
        break; }
    }
}

// ---------------------------------------------------------------------------
// scale/shift from accumulated stats
// ---------------------------------------------------------------------------
__global__ void scale_kernel(int stage,
    const float* __restrict__ bn_hf1, const float* __restrict__ bn_hf2,
    const float* __restrict__ bn_phu1, const float* __restrict__ bn_phu2,
    const float* __restrict__ bn_phl1, const float* __restrict__ bn_phl2,
    const float* __restrict__ bn_fd1, const float* __restrict__ bn_fd2,
    const float* __restrict__ bn_hd1, const float* __restrict__ bn_hd2,
    const float* __restrict__ bn_fu, const float* __restrict__ bn_hu,
    const float* __restrict__ bn_pu, float* __restrict__ ws)
{
    int t = threadIdx.x;
    float* sumA   = ws + (size_t)NSLOT * NPOS;
    float* sumqA  = sumA + NSTAT;
    float* scaleA = sumqA + NSTAT;
    float* shiftA = scaleA + NSTAT;
    int stat, local, co;
    const float* bn;
    if (stage == 1) {
        if (t >= 160) return;
        stat = t;
        if      (t < 20) { bn = bn_hf1;  local = t;      co = 20; }
        else if (t < 50) { bn = bn_fd1;  local = t - 20; co = 30; }
        else if (t < 70) { bn = bn_phu1; local = t - 50; co = 20; }
        else if (t < 90) { bn = bn_phl1; local = t - 70; co = 20; }
        else             { bn = bn_hd1;  local = t - 90; co = 70; }
    } else if (stage == 2) {
        if (t >= 130) return;
        stat = 160 + t;
        if      (t < 10) { bn = bn_hf2;  local = t;      co = 10; }
        else if (t < 40) { bn = bn_fd2;  local = t - 10; co = 30; }
        else if (t < 50) { bn = bn_phu2; local = t - 40; co = 10; }
        else if (t < 60) { bn = bn_phl2; local = t - 50; co = 10; }
        else             { bn = bn_hd2;  local = t - 60; co = 70; }
    } else {
        if (t >= 120) return;
        stat = 290 + t;
        if      (t < 20) { bn = bn_fu; local = t;      co = 20; }
        else if (t < 50) { bn = bn_hu; local = t - 20; co = 30; }
        else             { bn = bn_pu; local = t - 50; co = 70; }
    }
    float n  = (float)NPOS;
    float m  = sumA[stat] / n;
    float v  = sumqA[stat] / n - m * m;
    float g  = bn[local];
    float bt = bn[co + local];
    float sc = g * rsqrtf(v + EPSV);
    scaleA[stat] = sc;
    shiftA[stat] = bt - m * sc;
}

// ---------------------------------------------------------------------------
// Stage 2: hf2, fd2, phu2, phl2, hd2  (bn+relu stage-1 on the fly)
// ---------------------------------------------------------------------------
__global__ void __launch_bounds__(256) stage2_kernel(
    const float* __restrict__ w_hf2, const float* __restrict__ w_fd2,
    const float* __restrict__ w_phu2, const float* __restrict__ w_phl2,
    const float* __restrict__ w_hd2, float* __restrict__ ws)
{
    __shared__ float red[4 * 70 * 2];
    int pos = blockIdx.x * 256 + threadIdx.x;
    float* y     = ws;
    float* sumA  = ws + (size_t)NSLOT * NPOS;
    float* sumqA = sumA + NSTAT;
    const float* scaleA = sumqA + NSTAT;
    const float* shiftA = scaleA + NSTAT;

    switch (blockIdx.y) {
    case 0: { // hf2: hf1(20) -> 10
        const float* src = y + (size_t)S1_HF1 * NPOS + pos;
        conv_cbr<20, 10>([&](int c) {
            float v = fmaf(src[c * NPOS], scaleA[S1_HF1 + c], shiftA[S1_HF1 + c]);
            return v > 0.f ? v : 0.f; },
            w_hf2, y + (size_t)S2_HF2 * NPOS, pos, sumA, sumqA, S2_HF2, red);
        break; }
    case 1: { // fd2: fd1(30) -> 30
        const float* src = y + (size_t)S1_FD1 * NPOS + pos;
        conv_cbr<30, 30>([&](int c) {
            float v = fmaf(src[c * NPOS], scaleA[S1_FD1 + c], shiftA[S1_FD1 + c]);
            return v > 0.f ? v : 0.f; },
            w_fd2, y + (size_t)S2_FD2 * NPOS, pos, sumA, sumqA, S2_FD2, red);
        break; }
    case 2: { // phu2: phu1(20) -> 10
        const float* src = y + (size_t)S1_PHU1 * NPOS + pos;
        conv_cbr<20, 10>([&](int c) {
            float v = fmaf(src[c * NPOS], scaleA[S1_PHU1 + c], shiftA[S1_PHU1 + c]);
            return v > 0.f ? v : 0.f; },
            w_phu2, y + (size_t)S2_PHU2 * NPOS, pos, sumA, sumqA, S2_PHU2, red);
        break; }
    case 3: { // phl2: phl1(20) -> 10
        const float* src = y + (size_t)S1_PHL1 * NPOS + pos;
        conv_cbr<20, 10>([&](int c) {
            float v = fmaf(src[c * NPOS], scaleA[S1_PHL1 + c], shiftA[S1_PHL1 + c]);
            return v > 0.f ? v : 0.f; },
            w_phl2, y + (size_t)S2_PHL2 * NPOS, pos, sumA, sumqA, S2_PHL2, red);
        break; }
    default: { // hd2: hd1(70) -> 70
        const float* src = y + (size_t)S1_HD1 * NPOS + pos;
        conv_cbr<70, 70>([&](int c) {
            float v = fmaf(src[c * NPOS], scaleA[S1_HD1 + c], shiftA[S1_HD1 + c]);
            return v > 0.f ? v : 0.f; },
            w_hd2, y + (size_t)S2_HD2 * NPOS, pos, sumA, sumqA, S2_HD2, red);
        break; }
    }
}

// ---------------------------------------------------------------------------
// Stage 3: fu, hu, pu (composite residual inputs gathered on the fly)
// ---------------------------------------------------------------------------
__global__ void __launch_bounds__(256) stage3_kernel(
    const float* __restrict__ xp, const float* __restrict__ xh,
    const float* __restrict__ xf, const float* __restrict__ p_fea,
    const float* __restrict__ h_fea, const float* __restrict__ f_fea,
    const float* __restrict__ w_fu, const float* __restrict__ w_hu,
    const float* __restrict__ w_pu, float* __restrict__ ws)
{
    __shared__ float red[4 * 70 * 2];
    int pos = blockIdx.x * 256 + threadIdx.x;
    int b = (pos >= HW) ? 1 : 0;
    int s = pos - b * HW;
    float* y     = ws;
    float* sumA  = ws + (size_t)NSLOT * NPOS;
    float* sumqA = sumA + NSTAT;
    const float* scaleA = sumqA + NSTAT;
    const float* shiftA = scaleA + NSTAT;

    switch (blockIdx.y) {
    case 0: { // fu: [f_fea; xf_new] (266) -> 20 ; xf_new = bnrelu(hf2) + xf1
        const float* fb   = f_fea + (size_t)b * 256 * HW + s;
        const float* yhf2 = y + (size_t)S2_HF2 * NPOS + pos;
        const float* xf1  = xf + ((size_t)b * 20 + 10) * HW + s;
        conv_cbr<266, 20>([&](int c) {
            if (c < 256) return fb[c * HW];
            int cc = c - 256;
            float v = fmaf(yhf2[cc * NPOS], scaleA[S2_HF2 + cc], shiftA[S2_HF2 + cc]);
            v = v > 0.f ? v : 0.f;
            return v + xf1[cc * HW]; },
            w_fu, y + (size_t)S3_FU * NPOS, pos, sumA, sumqA, ST3_FU, red);
        break; }
    case 1: { // hu: [h_fea; xhu; xhl] (276) -> 30
        const float* hb    = h_fea + (size_t)b * 256 * HW + s;
        const float* yphu2 = y + (size_t)S2_PHU2 * NPOS + pos;
        const float* yphl2 = y + (size_t)S2_PHL2 * NPOS + pos;
        const float* yfd2  = y + (size_t)S2_FD2 * NPOS + pos;
        const float* xh1b  = xh + ((size_t)b * 30 + 10) * HW + s;
        conv_cbr<276, 30>([&](int c) {
            if (c < 256) return hb[c * HW];
            if (c < 266) {
                int cc = c - 256;
                float a = fmaf(yphu2[cc * NPOS], scaleA[S2_PHU2 + cc], shiftA[S2_PHU2 + cc]);
                a = a > 0.f ? a : 0.f;
                float f = fmaf(yfd2[(10 + cc) * NPOS], scaleA[S2_FD2 + 10 + cc], shiftA[S2_FD2 + 10 + cc]);
                f = f > 0.f ? f : 0.f;
                return xh1b[cc * HW] + a + f;
            }
            int cc = c - 266;
            float a = fmaf(yphl2[cc * NPOS], scaleA[S2_PHL2 + cc], shiftA[S2_PHL2 + cc]);
            a = a > 0.f ? a : 0.f;
            float f = fmaf(yfd2[(20 + cc) * NPOS], scaleA[S2_FD2 + 20 + cc], shiftA[S2_FD2 + 20 + cc]);
            f = f > 0.f ? f : 0.f;
            return xh1b[(10 + cc) * HW] + a + f; },
            w_hu, y + (size_t)S3_HU * NPOS, pos, sumA, sumqA, ST3_HU, red);
        break; }
    default: { // pu: [p_fea; xp_new(60)] (316) -> 70 ; xp_new = xp[1:7] + bnrelu(hd2)[10:70]
        const float* pb   = p_fea + (size_t)b * 256 * HW + s;
        const float* yhd2 = y + (size_t)S2_HD2 * NPOS + pos;
        const float* xpb  = xp + ((size_t)b * 70 + 10) * HW + s;
        conv_cbr<316, 70>([&](int c) {
            if (c < 256) return pb[c * HW];
            int cc = c - 256;
            float v = fmaf(yhd2[(10 + cc) * NPOS], scaleA[S2_HD2 + 10 + cc], shiftA[S2_HD2 + 10 + cc]);
            v = v > 0.f ? v : 0.f;
            return v + xpb[cc * HW]; },
            w_pu, y + (size_t)S3_PU * NPOS, pos, sumA, sumqA, ST3_PU, red);
        break; }
    }
}

// ---------------------------------------------------------------------------
// Final: bn+relu all 220 output channels
// out = concat([xp_upd(70), xh_upd(30), xf_upd(20), xfh(30), xhp(70)])
// ---------------------------------------------------------------------------
__global__ void __launch_bounds__(256) final_kernel(const float* __restrict__ ws,
                                                    float* __restrict__ out)
{
    int pos = blockIdx.x * 256 + threadIdx.x;
    int c = blockIdx.y;
    const float* sumA   = ws + (size_t)NSLOT * NPOS;
    const float* scaleA = sumA + 2 * NSTAT;
    const float* shiftA = scaleA + NSTAT;
    int slot, stat;
    if      (c < 70)  { slot = S3_PU  + c;         stat = ST3_PU  + c;         }
    else if (c < 100) { slot = S3_HU  + (c - 70);  stat = ST3_HU  + (c - 70);  }
    else if (c < 120) { slot = S3_FU  + (c - 100); stat = ST3_FU  + (c - 100); }
    else if (c < 150) { slot = S2_FD2 + (c - 120); stat = S2_FD2 + (c - 120);  }
    else              { slot = S2_HD2 + (c - 150); stat = S2_HD2 + (c - 150);  }
    float v = fmaf(ws[(size_t)slot * NPOS + pos], scaleA[stat], shiftA[stat]);
    v = v > 0.f ? v : 0.f;
    int b = (pos >= HW) ? 1 : 0;
    int s = pos - b * HW;
    out[((size_t)b * 220 + c) * HW + s] = v;
}

// ---------------------------------------------------------------------------
extern "C" void kernel_launch(void* const* d_in, const int* in_sizes, int n_in,
                              void* d_out, int out_size, void* d_ws, size_t ws_size,
                              hipStream_t stream)
{
    const float* xp     = (const float*)d_in[0];
    const float* xh     = (const float*)d_in[1];
    const float* xf     = (const float*)d_in[2];
    const float* p_fea  = (const float*)d_in[3];
    const float* h_fea  = (const float*)d_in[4];
    const float* f_fea  = (const float*)d_in[5];
    const float* w_hf1  = (const float*)d_in[6];  const float* bn_hf1  = (const float*)d_in[7];
    const float* w_hf2  = (const float*)d_in[8];  const float* bn_hf2  = (const float*)d_in[9];
    const float* w_phu1 = (const float*)d_in[10]; const float* bn_phu1 = (const float*)d_in[11];
    const float* w_phu2 = (const float*)d_in[12]; const float* bn_phu2 = (const float*)d_in[13];
    const float* w_phl1 = (const float*)d_in[14]; const float* bn_phl1 = (const float*)d_in[15];
    const float* w_phl2 = (const float*)d_in[16]; const float* bn_phl2 = (const float*)d_in[17];
    const float* w_fd1  = (const float*)d_in[18]; const float* bn_fd1  = (const float*)d_in[19];
    const float* w_fd2  = (const float*)d_in[20]; const float* bn_fd2  = (const float*)d_in[21];
    const float* w_hd1  = (const float*)d_in[22]; const float* bn_hd1  = (const float*)d_in[23];
    const float* w_hd2  = (const float*)d_in[24]; const float* bn_hd2  = (const float*)d_in[25];
    const float* w_fu   = (const float*)d_in[26]; const float* bn_fu   = (const float*)d_in[27];
    const float* w_hu   = (const float*)d_in[28]; const float* bn_hu   = (const float*)d_in[29];
    const float* w_pu   = (const float*)d_in[30]; const float* bn_pu   = (const float*)d_in[31];

    float* ws  = (float*)d_ws;
    float* out = (float*)d_out;

    size_t need_bytes = ((size_t)NSLOT * NPOS + 4 * NSTAT) * sizeof(float);
    if (ws_size < need_bytes) return;  // workspace too small -> clean failure

    // zero sum/sumsq accumulators (ws is poisoned 0xAA before every launch)
    hipMemsetAsync(ws + (size_t)NSLOT * NPOS, 0, 2 * NSTAT * sizeof(float), stream);

    dim3 blk(256);
    stage1_kernel<<<dim3(NBLK, 5), blk, 0, stream>>>(xp, xh, xf, p_fea, h_fea,
                                                     w_hf1, w_fd1, w_phu1, w_phl1, w_hd1, ws);
    scale_kernel<<<1, 256, 0, stream>>>(1, bn_hf1, bn_hf2, bn_phu1, bn_phu2, bn_phl1, bn_phl2,
                                        bn_fd1, bn_fd2, bn_hd1, bn_hd2, bn_fu, bn_hu, bn_pu, ws);
    stage2_kernel<<<dim3(NBLK, 5), blk, 0, stream>>>(w_hf2, w_fd2, w_phu2, w_phl2, w_hd2, ws);
    scale_kernel<<<1, 256, 0, stream>>>(2, bn_hf1, bn_hf2, bn_phu1, bn_phu2, bn_phl1, bn_phl2,
                                        bn_fd1, bn_fd2, bn_hd1, bn_hd2, bn_fu, bn_hu, bn_pu, ws);
    stage3_kernel<<<dim3(NBLK, 3), blk, 0, stream>>>(xp, xh, xf, p_fea, h_fea, f_fea,
                                                     w_fu, w_hu, w_pu, ws);
    scale_kernel<<<1, 256, 0, stream>>>(3, bn_hf1, bn_hf2, bn_phu1, bn_phu2, bn_phl1, bn_phl2,
                                        bn_fd1, bn_fd2, bn_hd1, bn_hd2, bn_fu, bn_hu, bn_pu, ws);
    final_kernel<<<dim3(NBLK, 220), blk, 0, stream>>>(ws, out);
}

// Round 2
// 748.715 us; speedup vs baseline: 1.4081x; 1.4081x over previous
//
#include <hip/hip_runtime.h>

#define HW   36864      // 192*192
#define NPOS 73728      // B*HW, B=2
#define EPSV 1e-5f

// channel-slot layout in workspace (each slot = NPOS floats)
#define S1_HF1  0
#define S1_FD1  20
#define S1_PHU1 50
#define S1_PHL1 70
#define S1_HD1  90
#define S2_HF2  160
#define S2_FD2  170
#define S2_PHU2 200
#define S2_PHL2 210
#define S2_HD2  220
#define S3_FU   0       // reuse stage-1 slots (dead by stage 3)
#define S3_HU   20
#define S3_PU   50
#define ST3_FU  290     // stat-channel bases for stage 3
#define ST3_HU  310
#define ST3_PU  340
#define NSLOT 290
#define NSTAT 410

__device__ __forceinline__ float2 ld2(const float* p) { return *(const float2*)p; }

__device__ __forceinline__ float2 bnrelu2(float2 v, float sc, float sh) {
    float2 r;
    r.x = fmaf(v.x, sc, sh); r.y = fmaf(v.y, sc, sh);
    r.x = r.x > 0.f ? r.x : 0.f;
    r.y = r.y > 0.f ? r.y : 0.f;
    return r;
}

// ---------------------------------------------------------------------------
// Per-position conv + stats. Each thread owns TWO positions (float2).
// Software-pipelined CHUNK-channel loop: loads for chunk k+1 issue before the
// FMA block of chunk k -> >=1120 cy of FMAs in flight per 8 outstanding loads,
// covering ~900 cy HBM latency even at low occupancy.
// ---------------------------------------------------------------------------
template<int CIN, int COUT, class F>
__device__ __forceinline__ void conv2(F fetch, const float* __restrict__ w,
                                      float* __restrict__ y, int p,
                                      float* __restrict__ sumA,
                                      float* __restrict__ sumqA,
                                      int stat0, float* red)
{
    constexpr int CHUNK = 8;
    float2 acc[COUT];
#pragma unroll
    for (int o = 0; o < COUT; ++o) acc[o] = make_float2(0.f, 0.f);

    constexpr int MAIN = (CIN / CHUNK) * CHUNK;
    if (MAIN > 0) {
        float2 buf[CHUNK];
#pragma unroll
        for (int i = 0; i < CHUNK; ++i) buf[i] = fetch(i);
#pragma unroll 1
        for (int c0 = CHUNK; c0 < MAIN; c0 += CHUNK) {
            float2 nxt[CHUNK];
#pragma unroll
            for (int i = 0; i < CHUNK; ++i) nxt[i] = fetch(c0 + i);  // prefetch
#pragma unroll
            for (int i = 0; i < CHUNK; ++i) {
                const float* wc = w + (c0 - CHUNK + i);
#pragma unroll
                for (int o = 0; o < COUT; ++o) {
                    float wv = wc[o * CIN];
                    acc[o].x = fmaf(wv, buf[i].x, acc[o].x);
                    acc[o].y = fmaf(wv, buf[i].y, acc[o].y);
                }
            }
#pragma unroll
            for (int i = 0; i < CHUNK; ++i) buf[i] = nxt[i];
        }
#pragma unroll
        for (int i = 0; i < CHUNK; ++i) {      // drain last main chunk
            const float* wc = w + (MAIN - CHUNK + i);
#pragma unroll
            for (int o = 0; o < COUT; ++o) {
                float wv = wc[o * CIN];
                acc[o].x = fmaf(wv, buf[i].x, acc[o].x);
                acc[o].y = fmaf(wv, buf[i].y, acc[o].y);
            }
        }
    }
#pragma unroll
    for (int c = MAIN; c < CIN; ++c) {         // tail channels
        float2 x = fetch(c);
#pragma unroll
        for (int o = 0; o < COUT; ++o) {
            float wv = w[o * CIN + c];
            acc[o].x = fmaf(wv, x.x, acc[o].x);
            acc[o].y = fmaf(wv, x.y, acc[o].y);
        }
    }

#pragma unroll
    for (int o = 0; o < COUT; ++o)
        *(float2*)(y + (size_t)o * NPOS + p) = acc[o];

    int lane = threadIdx.x & 63;
    int wv_  = threadIdx.x >> 6;
#pragma unroll
    for (int o = 0; o < COUT; ++o) {
        float s = acc[o].x + acc[o].y;
        float q = acc[o].x * acc[o].x + acc[o].y * acc[o].y;
#pragma unroll
        for (int i = 1; i < 64; i <<= 1) {
            s += __shfl_xor(s, i, 64);
            q += __shfl_xor(q, i, 64);
        }
        if (lane == 0) {
            red[(wv_ * COUT + o) * 2]     = s;
            red[(wv_ * COUT + o) * 2 + 1] = q;
        }
    }
    __syncthreads();
    if (threadIdx.x < COUT) {
        int o = threadIdx.x;
        float s = 0.f, q = 0.f;
#pragma unroll
        for (int k = 0; k < 4; ++k) {
            s += red[(k * COUT + o) * 2];
            q += red[(k * COUT + o) * 2 + 1];
        }
        atomicAdd(&sumA[stat0 + o], s);
        atomicAdd(&sumqA[stat0 + o], q);
    }
}

// ---------------------------------------------------------------------------
// Stage 1: hf1, fd1(x2), phu1, phl1, hd1(x2)
// ---------------------------------------------------------------------------
__global__ void __launch_bounds__(256) stage1_kernel(
    const float* __restrict__ xp, const float* __restrict__ xh,
    const float* __restrict__ xf, const float* __restrict__ p_fea,
    const float* __restrict__ h_fea,
    const float* __restrict__ w_hf1, const float* __restrict__ w_fd1,
    const float* __restrict__ w_phu1, const float* __restrict__ w_phl1,
    const float* __restrict__ w_hd1, float* __restrict__ ws)
{
    __shared__ float red[4 * 40 * 2];
    int g = blockIdx.x * 256 + threadIdx.x;
    int p = g * 2;
    int b = (p >= HW) ? 1 : 0;
    int s = p - b * HW;
    float* y     = ws;
    float* sumA  = ws + (size_t)NSLOT * NPOS;
    float* sumqA = sumA + NSTAT;

    switch (blockIdx.y) {
    case 0: { // hf1: [xh1; xh2] (20) -> 20
        const float* xb = xh + ((size_t)b * 30 + 10) * HW + s;
        conv2<20, 20>([&](int c) { return ld2(xb + c * HW); },
                      w_hf1, y + (size_t)S1_HF1 * NPOS, p, sumA, sumqA, S1_HF1, red);
        break; }
    case 1: case 2: { // fd1: [h_fea; xf1] (266) -> 15+15
        int off = (blockIdx.y - 1) * 15;
        const float* hb  = h_fea + (size_t)b * 256 * HW + s;
        const float* xf1 = xf + ((size_t)b * 20 + 10) * HW + s;
        conv2<266, 15>([&](int c) { return (c < 256) ? ld2(hb + c * HW)
                                                     : ld2(xf1 + (c - 256) * HW); },
                       w_fd1 + off * 266, y + (size_t)(S1_FD1 + off) * NPOS, p,
                       sumA, sumqA, S1_FD1 + off, red);
        break; }
    case 3: { // phu1: xp[1:5] (40) -> 20
        const float* xb = xp + ((size_t)b * 70 + 10) * HW + s;
        conv2<40, 20>([&](int c) { return ld2(xb + c * HW); },
                      w_phu1, y + (size_t)S1_PHU1 * NPOS, p, sumA, sumqA, S1_PHU1, red);
        break; }
    case 4: { // phl1: xp[5:7] (20) -> 20
        const float* xb = xp + ((size_t)b * 70 + 50) * HW + s;
        conv2<20, 20>([&](int c) { return ld2(xb + c * HW); },
                      w_phl1, y + (size_t)S1_PHL1 * NPOS, p, sumA, sumqA, S1_PHL1, red);
        break; }
    default: { // hd1: [p_fea; xh1; xh2] (276) -> 35+35
        int off = (blockIdx.y - 5) * 35;
        const float* pb = p_fea + (size_t)b * 256 * HW + s;
        const float* xb = xh + ((size_t)b * 30 + 10) * HW + s;
        conv2<276, 35>([&](int c) { return (c < 256) ? ld2(pb + c * HW)
                                                     : ld2(xb + (c - 256) * HW); },
                       w_hd1 + off * 276, y + (size_t)(S1_HD1 + off) * NPOS, p,
                       sumA, sumqA, S1_HD1 + off, red);
        break; }
    }
}

// ---------------------------------------------------------------------------
// scale/shift from accumulated stats
// ---------------------------------------------------------------------------
__global__ void scale_kernel(int stage,
    const float* __restrict__ bn_hf1, const float* __restrict__ bn_hf2,
    const float* __restrict__ bn_phu1, const float* __restrict__ bn_phu2,
    const float* __restrict__ bn_phl1, const float* __restrict__ bn_phl2,
    const float* __restrict__ bn_fd1, const float* __restrict__ bn_fd2,
    const float* __restrict__ bn_hd1, const float* __restrict__ bn_hd2,
    const float* __restrict__ bn_fu, const float* __restrict__ bn_hu,
    const float* __restrict__ bn_pu, float* __restrict__ ws)
{
    int t = threadIdx.x;
    float* sumA   = ws + (size_t)NSLOT * NPOS;
    float* sumqA  = sumA + NSTAT;
    float* scaleA = sumqA + NSTAT;
    float* shiftA = scaleA + NSTAT;
    int stat, local, co;
    const float* bn;
    if (stage == 1) {
        if (t >= 160) return;
        stat = t;
        if      (t < 20) { bn = bn_hf1;  local = t;      co = 20; }
        else if (t < 50) { bn = bn_fd1;  local = t - 20; co = 30; }
        else if (t < 70) { bn = bn_phu1; local = t - 50; co = 20; }
        else if (t < 90) { bn = bn_phl1; local = t - 70; co = 20; }
        else             { bn = bn_hd1;  local = t - 90; co = 70; }
    } else if (stage == 2) {
        if (t >= 130) return;
        stat = 160 + t;
        if      (t < 10) { bn = bn_hf2;  local = t;      co = 10; }
        else if (t < 40) { bn = bn_fd2;  local = t - 10; co = 30; }
        else if (t < 50) { bn = bn_phu2; local = t - 40; co = 10; }
        else if (t < 60) { bn = bn_phl2; local = t - 50; co = 10; }
        else             { bn = bn_hd2;  local = t - 60; co = 70; }
    } else {
        if (t >= 120) return;
        stat = 290 + t;
        if      (t < 20) { bn = bn_fu; local = t;      co = 20; }
        else if (t < 50) { bn = bn_hu; local = t - 20; co = 30; }
        else             { bn = bn_pu; local = t - 50; co = 70; }
    }
    float n  = (float)NPOS;
    float m  = sumA[stat] / n;
    float v  = sumqA[stat] / n - m * m;
    float g  = bn[local];
    float bt = bn[co + local];
    float sc = g * rsqrtf(v + EPSV);
    scaleA[stat] = sc;
    shiftA[stat] = bt - m * sc;
}

// ---------------------------------------------------------------------------
// Stage 2: hf2, fd2, phu2, phl2, hd2(x2)  (bn+relu stage-1 on the fly)
// ---------------------------------------------------------------------------
__global__ void __launch_bounds__(256) stage2_kernel(
    const float* __restrict__ w_hf2, const float* __restrict__ w_fd2,
    const float* __restrict__ w_phu2, const float* __restrict__ w_phl2,
    const float* __restrict__ w_hd2, float* __restrict__ ws)
{
    __shared__ float red[4 * 40 * 2];
    int g = blockIdx.x * 256 + threadIdx.x;
    int p = g * 2;
    float* y     = ws;
    float* sumA  = ws + (size_t)NSLOT * NPOS;
    float* sumqA = sumA + NSTAT;
    const float* scaleA = sumqA + NSTAT;
    const float* shiftA = scaleA + NSTAT;

    switch (blockIdx.y) {
    case 0: { // hf2: hf1(20) -> 10
        const float* src = y + (size_t)S1_HF1 * NPOS + p;
        conv2<20, 10>([&](int c) {
            return bnrelu2(ld2(src + (size_t)c * NPOS), scaleA[S1_HF1 + c], shiftA[S1_HF1 + c]); },
            w_hf2, y + (size_t)S2_HF2 * NPOS, p, sumA, sumqA, S2_HF2, red);
        break; }
    case 1: { // fd2: fd1(30) -> 30
        const float* src = y + (size_t)S1_FD1 * NPOS + p;
        conv2<30, 30>([&](int c) {
            return bnrelu2(ld2(src + (size_t)c * NPOS), scaleA[S1_FD1 + c], shiftA[S1_FD1 + c]); },
            w_fd2, y + (size_t)S2_FD2 * NPOS, p, sumA, sumqA, S2_FD2, red);
        break; }
    case 2: { // phu2: phu1(20) -> 10
        const float* src = y + (size_t)S1_PHU1 * NPOS + p;
        conv2<20, 10>([&](int c) {
            return bnrelu2(ld2(src + (size_t)c * NPOS), scaleA[S1_PHU1 + c], shiftA[S1_PHU1 + c]); },
            w_phu2, y + (size_t)S2_PHU2 * NPOS, p, sumA, sumqA, S2_PHU2, red);
        break; }
    case 3: { // phl2: phl1(20) -> 10
        const float* src = y + (size_t)S1_PHL1 * NPOS + p;
        conv2<20, 10>([&](int c) {
            return bnrelu2(ld2(src + (size_t)c * NPOS), scaleA[S1_PHL1 + c], shiftA[S1_PHL1 + c]); },
            w_phl2, y + (size_t)S2_PHL2 * NPOS, p, sumA, sumqA, S2_PHL2, red);
        break; }
    default: { // hd2: hd1(70) -> 35+35
        int off = (blockIdx.y - 4) * 35;
        const float* src = y + (size_t)S1_HD1 * NPOS + p;
        conv2<70, 35>([&](int c) {
            return bnrelu2(ld2(src + (size_t)c * NPOS), scaleA[S1_HD1 + c], shiftA[S1_HD1 + c]); },
            w_hd2 + off * 70, y + (size_t)(S2_HD2 + off) * NPOS, p,
            sumA, sumqA, S2_HD2 + off, red);
        break; }
    }
}

// ---------------------------------------------------------------------------
// Stage 3: fu, hu, pu(x2)
// ---------------------------------------------------------------------------
__global__ void __launch_bounds__(256) stage3_kernel(
    const float* __restrict__ xp, const float* __restrict__ xh,
    const float* __restrict__ xf, const float* __restrict__ p_fea,
    const float* __restrict__ h_fea, const float* __restrict__ f_fea,
    const float* __restrict__ w_fu, const float* __restrict__ w_hu,
    const float* __restrict__ w_pu, float* __restrict__ ws)
{
    __shared__ float red[4 * 40 * 2];
    int g = blockIdx.x * 256 + threadIdx.x;
    int p = g * 2;
    int b = (p >= HW) ? 1 : 0;
    int s = p - b * HW;
    float* y     = ws;
    float* sumA  = ws + (size_t)NSLOT * NPOS;
    float* sumqA = sumA + NSTAT;
    const float* scaleA = sumqA + NSTAT;
    const float* shiftA = scaleA + NSTAT;

    switch (blockIdx.y) {
    case 0: { // fu: [f_fea; xf_new] (266) -> 20 ; xf_new = bnrelu(hf2) + xf1
        const float* fb   = f_fea + (size_t)b * 256 * HW + s;
        const float* yhf2 = y + (size_t)S2_HF2 * NPOS + p;
        const float* xf1  = xf + ((size_t)b * 20 + 10) * HW + s;
        conv2<266, 20>([&](int c) {
            if (c < 256) return ld2(fb + c * HW);
            int cc = c - 256;
            float2 v = bnrelu2(ld2(yhf2 + (size_t)cc * NPOS),
                               scaleA[S2_HF2 + cc], shiftA[S2_HF2 + cc]);
            float2 r0 = ld2(xf1 + cc * HW);
            return make_float2(v.x + r0.x, v.y + r0.y); },
            w_fu, y + (size_t)S3_FU * NPOS, p, sumA, sumqA, ST3_FU, red);
        break; }
    case 1: { // hu: [h_fea; xhu; xhl] (276) -> 30
        const float* hb    = h_fea + (size_t)b * 256 * HW + s;
        const float* yphu2 = y + (size_t)S2_PHU2 * NPOS + p;
        const float* yphl2 = y + (size_t)S2_PHL2 * NPOS + p;
        const float* yfd2  = y + (size_t)S2_FD2 * NPOS + p;
        const float* xh1b  = xh + ((size_t)b * 30 + 10) * HW + s;
        conv2<276, 30>([&](int c) {
            if (c < 256) return ld2(hb + c * HW);
            if (c < 266) {
                int cc = c - 256;
                float2 a = bnrelu2(ld2(yphu2 + (size_t)cc * NPOS),
                                   scaleA[S2_PHU2 + cc], shiftA[S2_PHU2 + cc]);
                float2 f = bnrelu2(ld2(yfd2 + (size_t)(10 + cc) * NPOS),
                                   scaleA[S2_FD2 + 10 + cc], shiftA[S2_FD2 + 10 + cc]);
                float2 r0 = ld2(xh1b + cc * HW);
                return make_float2(r0.x + a.x + f.x, r0.y + a.y + f.y);
            }
            int cc = c - 266;
            float2 a = bnrelu2(ld2(yphl2 + (size_t)cc * NPOS),
                               scaleA[S2_PHL2 + cc], shiftA[S2_PHL2 + cc]);
            float2 f = bnrelu2(ld2(yfd2 + (size_t)(20 + cc) * NPOS),
                               scaleA[S2_FD2 + 20 + cc], shiftA[S2_FD2 + 20 + cc]);
            float2 r0 = ld2(xh1b + (10 + cc) * HW);
            return make_float2(r0.x + a.x + f.x, r0.y + a.y + f.y); },
            w_hu, y + (size_t)S3_HU * NPOS, p, sumA, sumqA, ST3_HU, red);
        break; }
    default: { // pu: [p_fea; xp_new(60)] (316) -> 35+35
        int off = (blockIdx.y - 2) * 35;
        const float* pb   = p_fea + (size_t)b * 256 * HW + s;
        const float* yhd2 = y + (size_t)S2_HD2 * NPOS + p;
        const float* xpb  = xp + ((size_t)b * 70 + 10) * HW + s;
        conv2<316, 35>([&](int c) {
            if (c < 256) return ld2(pb + c * HW);
            int cc = c - 256;
            float2 v = bnrelu2(ld2(yhd2 + (size_t)(10 + cc) * NPOS),
                               scaleA[S2_HD2 + 10 + cc], shiftA[S2_HD2 + 10 + cc]);
            float2 r0 = ld2(xpb + cc * HW);
            return make_float2(v.x + r0.x, v.y + r0.y); },
            w_pu + off * 316, y + (size_t)(S3_PU + off) * NPOS, p,
            sumA, sumqA, ST3_PU + off, red);
        break; }
    }
}

// ---------------------------------------------------------------------------
// Final: bn+relu all 220 output channels, float4
// out = concat([xp_upd(70), xh_upd(30), xf_upd(20), xfh(30), xhp(70)])
// ---------------------------------------------------------------------------
__global__ void __launch_bounds__(256) final_kernel(const float* __restrict__ ws,
                                                    float* __restrict__ out)
{
    int g = blockIdx.x * 256 + threadIdx.x;
    int p = g * 4;
    int c = blockIdx.y;
    const float* sumA   = ws + (size_t)NSLOT * NPOS;
    const float* scaleA = sumA + 2 * NSTAT;
    const float* shiftA = scaleA + NSTAT;
    int slot, stat;
    if      (c < 70)  { slot = S3_PU  + c;         stat = ST3_PU  + c;         }
    else if (c < 100) { slot = S3_HU  + (c - 70);  stat = ST3_HU  + (c - 70);  }
    else if (c < 120) { slot = S3_FU  + (c - 100); stat = ST3_FU  + (c - 100); }
    else if (c < 150) { slot = S2_FD2 + (c - 120); stat = S2_FD2 + (c - 120);  }
    else              { slot = S2_HD2 + (c - 150); stat = S2_HD2 + (c - 150);  }
    float4 v = *(const float4*)(ws + (size_t)slot * NPOS + p);
    float sc = scaleA[stat], sh = shiftA[stat];
    v.x = fmaf(v.x, sc, sh); v.x = v.x > 0.f ? v.x : 0.f;
    v.y = fmaf(v.y, sc, sh); v.y = v.y > 0.f ? v.y : 0.f;
    v.z = fmaf(v.z, sc, sh); v.z = v.z > 0.f ? v.z : 0.f;
    v.w = fmaf(v.w, sc, sh); v.w = v.w > 0.f ? v.w : 0.f;
    int b = (p >= HW) ? 1 : 0;
    int s = p - b * HW;
    *(float4*)(out + ((size_t)b * 220 + c) * HW + s) = v;
}

// ---------------------------------------------------------------------------
extern "C" void kernel_launch(void* const* d_in, const int* in_sizes, int n_in,
                              void* d_out, int out_size, void* d_ws, size_t ws_size,
                              hipStream_t stream)
{
    const float* xp     = (const float*)d_in[0];
    const float* xh     = (const float*)d_in[1];
    const float* xf     = (const float*)d_in[2];
    const float* p_fea  = (const float*)d_in[3];
    const float* h_fea  = (const float*)d_in[4];
    const float* f_fea  = (const float*)d_in[5];
    const float* w_hf1  = (const float*)d_in[6];  const float* bn_hf1  = (const float*)d_in[7];
    const float* w_hf2  = (const float*)d_in[8];  const float* bn_hf2  = (const float*)d_in[9];
    const float* w_phu1 = (const float*)d_in[10]; const float* bn_phu1 = (const float*)d_in[11];
    const float* w_phu2 = (const float*)d_in[12]; const float* bn_phu2 = (const float*)d_in[13];
    const float* w_phl1 = (const float*)d_in[14]; const float* bn_phl1 = (const float*)d_in[15];
    const float* w_phl2 = (const float*)d_in[16]; const float* bn_phl2 = (const float*)d_in[17];
    const float* w_fd1  = (const float*)d_in[18]; const float* bn_fd1  = (const float*)d_in[19];
    const float* w_fd2  = (const float*)d_in[20]; const float* bn_fd2  = (const float*)d_in[21];
    const float* w_hd1  = (const float*)d_in[22]; const float* bn_hd1  = (const float*)d_in[23];
    const float* w_hd2  = (const float*)d_in[24]; const float* bn_hd2  = (const float*)d_in[25];
    const float* w_fu   = (const float*)d_in[26]; const float* bn_fu   = (const float*)d_in[27];
    const float* w_hu   = (const float*)d_in[28]; const float* bn_hu   = (const float*)d_in[29];
    const float* w_pu   = (const float*)d_in[30]; const float* bn_pu   = (const float*)d_in[31];

    float* ws  = (float*)d_ws;
    float* out = (float*)d_out;

    size_t need_bytes = ((size_t)NSLOT * NPOS + 4 * NSTAT) * sizeof(float);
    if (ws_size < need_bytes) return;

    hipMemsetAsync(ws + (size_t)NSLOT * NPOS, 0, 2 * NSTAT * sizeof(float), stream);

    dim3 blk(256);
    const int GX = NPOS / 512;   // 144 blocks, 2 positions/thread
    stage1_kernel<<<dim3(GX, 7), blk, 0, stream>>>(xp, xh, xf, p_fea, h_fea,
                                                   w_hf1, w_fd1, w_phu1, w_phl1, w_hd1, ws);
    scale_kernel<<<1, 256, 0, stream>>>(1, bn_hf1, bn_hf2, bn_phu1, bn_phu2, bn_phl1, bn_phl2,
                                        bn_fd1, bn_fd2, bn_hd1, bn_hd2, bn_fu, bn_hu, bn_pu, ws);
    stage2_kernel<<<dim3(GX, 6), blk, 0, stream>>>(w_hf2, w_fd2, w_phu2, w_phl2, w_hd2, ws);
    scale_kernel<<<1, 256, 0, stream>>>(2, bn_hf1, bn_hf2, bn_phu1, bn_phu2, bn_phl1, bn_phl2,
                                        bn_fd1, bn_fd2, bn_hd1, bn_hd2, bn_fu, bn_hu, bn_pu, ws);
    stage3_kernel<<<dim3(GX, 4), blk, 0, stream>>>(xp, xh, xf, p_fea, h_fea, f_fea,
                                                   w_fu, w_hu, w_pu, ws);
    scale_kernel<<<1, 256, 0, stream>>>(3, bn_hf1, bn_hf2, bn_phu1, bn_phu2, bn_phl1, bn_phl2,
                                        bn_fd1, bn_fd2, bn_hd1, bn_hd2, bn_fu, bn_hu, bn_pu, ws);
    final_kernel<<<dim3(NPOS / 1024, 220), blk, 0, stream>>>(ws, out);
}